// Round 2
// baseline (941.208 us; speedup 1.0000x reference)
//
#include <hip/hip_runtime.h>
#include <hip/hip_bf16.h>
#include <stdint.h>

// Net_61272003445332: GraphSAGE w/ LSTM aggregator, N=20000, K=16,
// dims: l0 (din=64,dout=128), l1 (128,128), l2 (128,32).
// All harness I/O is FP32 (reference is jnp.float32). MFMA needs bf16, so
// weights are converted fp32->bf16 once per launch into ws; features and the
// precomputed P = feat@Wih.T + (bih+bhh) are stored bf16; S and gate math fp32.

#define N_NODES 20000
#define KNE 16

typedef __bf16 bf16x8 __attribute__((ext_vector_type(8)));
typedef float f32x4 __attribute__((ext_vector_type(4)));

__device__ __forceinline__ bf16x8 ldb8(const __hip_bfloat16* p) {
  uint4 u = *reinterpret_cast<const uint4*>(p);
  return __builtin_bit_cast(bf16x8, u);
}

__device__ __forceinline__ float sigf(float x) {
  x = fminf(fmaxf(x, -30.f), 30.f);
  return 1.f / (1.f + __expf(-x));
}

__device__ __forceinline__ float tanhf_(float x) {
  x = fminf(fmaxf(x, -15.f), 15.f);
  float e = __expf(2.f * x);
  return (e - 1.f) / (e + 1.f);
}

__global__ void build_feat0(const float* __restrict__ p,
                            __hip_bfloat16* __restrict__ f0) {
  int i = blockIdx.x * 256 + threadIdx.x;
  if (i >= N_NODES * 64) return;
  int n = i >> 6, c = i & 63;
  float v = (c == 0) ? ((float)KNE / (float)N_NODES) : p[n * 63 + c - 1];
  f0[i] = __float2bfloat16(v);
}

// Convert 4 fp32 weight tensors to bf16 (one launch per layer).
__global__ void cvt4(const float* __restrict__ s0, int n0,
                     const float* __restrict__ s1, int n1,
                     const float* __restrict__ s2, int n2,
                     const float* __restrict__ s3, int n3,
                     __hip_bfloat16* __restrict__ d0,
                     __hip_bfloat16* __restrict__ d1,
                     __hip_bfloat16* __restrict__ d2,
                     __hip_bfloat16* __restrict__ d3) {
  int i = blockIdx.x * 256 + threadIdx.x;
  if (i < n0) { d0[i] = __float2bfloat16(s0[i]); return; }
  i -= n0;
  if (i < n1) { d1[i] = __float2bfloat16(s1[i]); return; }
  i -= n1;
  if (i < n2) { d2[i] = __float2bfloat16(s2[i]); return; }
  i -= n2;
  if (i < n3) d3[i] = __float2bfloat16(s3[i]);
}

// P = feat@Wih.T + (bih+bhh)  -> bf16 [N,4*DIN]
// S = feat@Wself.T + b        -> f32  [N,DOUT]
template <int DIN, int DOUT>
__global__ __launch_bounds__(256, 2) void proj_kern(
    const __hip_bfloat16* __restrict__ feat,
    const __hip_bfloat16* __restrict__ Wih,   // bf16 [4*DIN, DIN]
    const float* __restrict__ bih,
    const float* __restrict__ bhh,
    const __hip_bfloat16* __restrict__ Wself, // bf16 [DOUT, DIN]
    const float* __restrict__ bvec,
    __hip_bfloat16* __restrict__ P, float* __restrict__ S) {
  constexpr int KB = DIN / 32;
  constexpr int CTP = 4 * DIN / 16;
  constexpr int CTS = DOUT / 16;
  const int n0 = blockIdx.x * 32;
  const int tid = threadIdx.x;
  const int wv = tid >> 6;
  const int lane = tid & 63;
  const int quad = lane >> 4;
  const int c16 = lane & 15;

  bf16x8 afr[2][KB];
#pragma unroll
  for (int rt = 0; rt < 2; ++rt)
#pragma unroll
    for (int kb = 0; kb < KB; ++kb)
      afr[rt][kb] =
          ldb8(feat + (size_t)(n0 + rt * 16 + c16) * DIN + kb * 32 + quad * 8);

  const f32x4 zz = {0.f, 0.f, 0.f, 0.f};
  for (int ct = wv; ct < CTP + CTS; ct += 4) {
    f32x4 a0 = zz, a1 = zz;
    const __hip_bfloat16* W;
    int row;
    if (ct < CTP) { W = Wih; row = ct * 16 + c16; }
    else          { W = Wself; row = (ct - CTP) * 16 + c16; }
#pragma unroll
    for (int kb = 0; kb < KB; ++kb) {
      bf16x8 b = ldb8(W + (size_t)row * DIN + kb * 32 + quad * 8);
      a0 = __builtin_amdgcn_mfma_f32_16x16x32_bf16(afr[0][kb], b, a0, 0, 0, 0);
      a1 = __builtin_amdgcn_mfma_f32_16x16x32_bf16(afr[1][kb], b, a1, 0, 0, 0);
    }
    if (ct < CTP) {
      int c = ct * 16 + c16;
      float bias = bih[c] + bhh[c];
#pragma unroll
      for (int r = 0; r < 4; ++r) {
        P[(size_t)(n0 + quad * 4 + r) * (4 * DIN) + c] =
            __float2bfloat16(a0[r] + bias);
        P[(size_t)(n0 + 16 + quad * 4 + r) * (4 * DIN) + c] =
            __float2bfloat16(a1[r] + bias);
      }
    } else {
      int c = (ct - CTP) * 16 + c16;
      float bias = bvec[c];
#pragma unroll
      for (int r = 0; r < 4; ++r) {
        S[(size_t)(n0 + quad * 4 + r) * DOUT + c] = a0[r] + bias;
        S[(size_t)(n0 + 16 + quad * 4 + r) * DOUT + c] = a1[r] + bias;
      }
    }
  }
}

// LSTM aggregation over 16 gathered P rows + fused fc epilogue.
// Block = 32 nodes, 4 waves; wave w owns gate-cols [w*DIN/4, (w+1)*DIN/4).
template <int DIN, int DOUT, bool RELU, typename OutT>
__global__ __launch_bounds__(256, 2) void lstm_fc_kern(
    const __hip_bfloat16* __restrict__ P,   // [N, 4*DIN] bf16
    const float* __restrict__ S,            // [N, DOUT] f32
    const __hip_bfloat16* __restrict__ Whh, // bf16 [4*DIN, DIN]
    const __hip_bfloat16* __restrict__ Wng, // bf16 [DOUT, DIN]
    const int* __restrict__ nidx,           // [N, 16]
    OutT* __restrict__ outp) {              // [N, DOUT]
  constexpr int KB = DIN / 32;
  constexpr int JJ = DIN / 64;  // 16-col tiles per gate per wave
  constexpr int CW = DIN / 4;   // gate cols per wave
  constexpr int PS = 4 * DIN + 8;
  constexpr int HS = DIN + 8;
  constexpr int CH = DIN / 2;   // 16B chunks per P row

  __shared__ __align__(16) __hip_bfloat16 Pl[32 * PS];
  __shared__ __align__(16) __hip_bfloat16 hl[32 * HS];
  __shared__ int idxl[32 * KNE];

  const int n0 = blockIdx.x * 32;
  const int tid = threadIdx.x;
  const int wv = tid >> 6;
  const int lane = tid & 63;
  const int quad = lane >> 4;
  const int c16 = lane & 15;

  for (int i = tid; i < 32 * KNE; i += 256) idxl[i] = nidx[n0 * KNE + i];

  float cst[2][JJ][4];
#pragma unroll
  for (int rt = 0; rt < 2; ++rt)
#pragma unroll
    for (int jj = 0; jj < JJ; ++jj)
#pragma unroll
      for (int r = 0; r < 4; ++r) cst[rt][jj][r] = 0.f;

  __syncthreads();  // idxl ready

  const f32x4 zz = {0.f, 0.f, 0.f, 0.f};
  for (int t = 0; t < KNE; ++t) {
    // stage gathered P rows into LDS (coalesced 16B chunks)
    for (int ch = tid; ch < 32 * CH; ch += 256) {
      int r = ch / CH, o = ch % CH;
      int src = idxl[r * KNE + t];
      *reinterpret_cast<uint4*>(&Pl[r * PS + o * 8]) =
          *reinterpret_cast<const uint4*>(P + (size_t)src * (4 * DIN) + o * 8);
    }
    __syncthreads();

    f32x4 acc[2][4][JJ];
#pragma unroll
    for (int rt = 0; rt < 2; ++rt)
#pragma unroll
      for (int gi = 0; gi < 4; ++gi)
#pragma unroll
        for (int jj = 0; jj < JJ; ++jj) acc[rt][gi][jj] = zz;

    if (t > 0) {  // h==0 at t==0
#pragma unroll
      for (int kb = 0; kb < KB; ++kb) {
        bf16x8 a0 = ldb8(&hl[(size_t)c16 * HS + kb * 32 + quad * 8]);
        bf16x8 a1 = ldb8(&hl[(size_t)(16 + c16) * HS + kb * 32 + quad * 8]);
#pragma unroll
        for (int gi = 0; gi < 4; ++gi)
#pragma unroll
          for (int jj = 0; jj < JJ; ++jj) {
            int wr = gi * DIN + wv * CW + jj * 16 + c16;
            bf16x8 b = ldb8(Whh + (size_t)wr * DIN + kb * 32 + quad * 8);
            acc[0][gi][jj] = __builtin_amdgcn_mfma_f32_16x16x32_bf16(
                a0, b, acc[0][gi][jj], 0, 0, 0);
            acc[1][gi][jj] = __builtin_amdgcn_mfma_f32_16x16x32_bf16(
                a1, b, acc[1][gi][jj], 0, 0, 0);
          }
      }
    }
    __syncthreads();  // all hl reads done before epilogue overwrites h

    // gates + state update; C/D layout: col=lane&15, row=quad*4+r
#pragma unroll
    for (int rt = 0; rt < 2; ++rt)
#pragma unroll
      for (int jj = 0; jj < JJ; ++jj)
#pragma unroll
        for (int r = 0; r < 4; ++r) {
          int m = rt * 16 + quad * 4 + r;
          int col = wv * CW + jj * 16 + c16;
          float gI = acc[rt][0][jj][r] + __bfloat162float(Pl[m * PS + col]);
          float gF = acc[rt][1][jj][r] + __bfloat162float(Pl[m * PS + DIN + col]);
          float gG = acc[rt][2][jj][r] + __bfloat162float(Pl[m * PS + 2 * DIN + col]);
          float gO = acc[rt][3][jj][r] + __bfloat162float(Pl[m * PS + 3 * DIN + col]);
          float cc = sigf(gF) * cst[rt][jj][r] + sigf(gI) * tanhf_(gG);
          cst[rt][jj][r] = cc;
          hl[m * HS + col] = __float2bfloat16(sigf(gO) * tanhf_(cc));
        }
    __syncthreads();  // h visible; Pl free for next stage
  }

  // fused fc: out = S + h@Wneigh.T (+ReLU), h in hl
  constexpr int NCT = DOUT / 16;
  for (int cb = wv; cb < 2 * NCT; cb += 4) {
    int rt = cb / NCT, ct = cb % NCT;
    f32x4 a = {0.f, 0.f, 0.f, 0.f};
#pragma unroll
    for (int kb = 0; kb < KB; ++kb) {
      bf16x8 af = ldb8(&hl[(size_t)(rt * 16 + c16) * HS + kb * 32 + quad * 8]);
      bf16x8 bf = ldb8(Wng + (size_t)(ct * 16 + c16) * DIN + kb * 32 + quad * 8);
      a = __builtin_amdgcn_mfma_f32_16x16x32_bf16(af, bf, a, 0, 0, 0);
    }
    int colc = ct * 16 + c16;
#pragma unroll
    for (int r = 0; r < 4; ++r) {
      int n = n0 + rt * 16 + quad * 4 + r;
      float v = a[r] + S[(size_t)n * DOUT + colc];
      if (RELU) v = fmaxf(v, 0.f);
      if constexpr (sizeof(OutT) == 2)
        outp[(size_t)n * DOUT + colc] = __float2bfloat16(v);
      else
        outp[(size_t)n * DOUT + colc] = v;
    }
  }
}

extern "C" void kernel_launch(void* const* d_in, const int* in_sizes, int n_in,
                              void* d_out, int out_size, void* d_ws,
                              size_t ws_size, hipStream_t stream) {
  (void)in_sizes; (void)n_in; (void)out_size; (void)ws_size;
  const float* p = (const float*)d_in[0];
  const int* nidx = (const int*)d_in[1];
  const float* L[3][7];
  for (int l = 0; l < 3; ++l)
    for (int j = 0; j < 7; ++j)
      L[l][j] = (const float*)d_in[2 + 7 * l + j];
  // per-layer params: 0=Wih 1=Whh 2=bih 3=bhh 4=Wself 5=Wneigh 6=b

  char* w = (char*)d_ws;
  __hip_bfloat16* feat0 = (__hip_bfloat16*)(w);             // N*64*2  = 2.56MB
  __hip_bfloat16* feat1 = (__hip_bfloat16*)(w + 2560000);   // N*128*2 = 5.12MB
  __hip_bfloat16* feat2 = (__hip_bfloat16*)(w + 7680000);   // N*128*2 = 5.12MB
  __hip_bfloat16* Pb    = (__hip_bfloat16*)(w + 12800000);  // N*512*2 = 20.48MB
  float*          Sb    = (float*)(w + 33280000);           // N*128*4 = 10.24MB
  __hip_bfloat16* wb    = (__hip_bfloat16*)(w + 43520000);  // bf16 weights

  // bf16 weight pool layout
  const int din_[3] = {64, 128, 128}, dout_[3] = {128, 128, 32};
  __hip_bfloat16 *Wih_b[3], *Whh_b[3], *Wself_b[3], *Wng_b[3];
  size_t off = 0;
  for (int l = 0; l < 3; ++l) {
    int din = din_[l], dout = dout_[l];
    Wih_b[l] = wb + off;   off += (size_t)4 * din * din;
    Whh_b[l] = wb + off;   off += (size_t)4 * din * din;
    Wself_b[l] = wb + off; off += (size_t)dout * din;
    Wng_b[l] = wb + off;   off += (size_t)dout * din;
  }
  for (int l = 0; l < 3; ++l) {
    int din = din_[l], dout = dout_[l];
    int n0 = 4 * din * din, n2 = dout * din;
    int tot = 2 * n0 + 2 * n2;
    cvt4<<<(tot + 255) / 256, 256, 0, stream>>>(
        L[l][0], n0, L[l][1], n0, L[l][4], n2, L[l][5], n2,
        Wih_b[l], Whh_b[l], Wself_b[l], Wng_b[l]);
  }

  build_feat0<<<(N_NODES * 64 + 255) / 256, 256, 0, stream>>>(p, feat0);

  // layer 0: din=64, dout=128
  proj_kern<64, 128><<<N_NODES / 32, 256, 0, stream>>>(
      feat0, Wih_b[0], L[0][2], L[0][3], Wself_b[0], L[0][6], Pb, Sb);
  lstm_fc_kern<64, 128, true, __hip_bfloat16><<<N_NODES / 32, 256, 0, stream>>>(
      Pb, Sb, Whh_b[0], Wng_b[0], nidx, feat1);

  // layer 1: din=128, dout=128
  proj_kern<128, 128><<<N_NODES / 32, 256, 0, stream>>>(
      feat1, Wih_b[1], L[1][2], L[1][3], Wself_b[1], L[1][6], Pb, Sb);
  lstm_fc_kern<128, 128, true, __hip_bfloat16><<<N_NODES / 32, 256, 0, stream>>>(
      Pb, Sb, Whh_b[1], Wng_b[1], nidx, feat2);

  // layer 2: din=128, dout=32 (no relu; final fp32 output)
  proj_kern<128, 32><<<N_NODES / 32, 256, 0, stream>>>(
      feat2, Wih_b[2], L[2][2], L[2][3], Wself_b[2], L[2][6], Pb, Sb);
  lstm_fc_kern<128, 32, false, float><<<N_NODES / 32, 256, 0, stream>>>(
      Pb, Sb, Whh_b[2], Wng_b[2], nidx, (float*)d_out);
}